// Round 12
// baseline (230.492 us; speedup 1.0000x reference)
//
#include <hip/hip_runtime.h>

#define NN 50000
#define NE 800000
#define ELLW 64

__device__ __forceinline__ float wredf(float v) {
    #pragma unroll
    for (int o = 32; o > 0; o >>= 1) v += __shfl_down(v, o, 64);
    return v;
}

// ---- ELL fill: R4-proven minimal shape (VGPR ~4, no LDS, max occupancy) ----
__global__ __launch_bounds__(256) void k_fill(
    const int* __restrict__ src, const int* __restrict__ dst,
    int* __restrict__ cursor, int* __restrict__ ell)
{
    int e = blockIdx.x * 256 + threadIdx.x;      // 3125*256 == NE exactly
    int s = src[e];
    int d = dst[e];
    int p = atomicAdd(&cursor[d], 1);            // compact cursor: proven 46us config
    if (p < ELLW) ell[d * ELLW + p] = s;         // deg max ~45 << 64
}

// ---- projection: 4 threads per node (short load chain) + fused sumsq + W collapse ----
// blocks 0..783: nodes; block 784: uvec/cvec. 64 nodes/block.
__global__ __launch_bounds__(256) void k_proj(
    const float* __restrict__ x,
    const float* __restrict__ W0, const float* __restrict__ W1,
    const float* __restrict__ cb0, const float* __restrict__ cb1,
    const float* __restrict__ L0, const float* __restrict__ lb0,
    const int* __restrict__ cursor, float* __restrict__ acc,
    float* __restrict__ uvec, float* __restrict__ cvec,
    float* __restrict__ gp)
{
    __shared__ float WA[1000];                   // W1@L0 [100][10]
    int t = threadIdx.x;
    for (int o = t; o < 1000; o += 256) {
        int j = o / 10, m = o % 10;
        float s = 0.f;
        for (int k = 0; k < 100; ++k) s += W1[j * 100 + k] * L0[k * 10 + m];
        WA[o] = s;
    }
    __syncthreads();
    if (blockIdx.x == 784) {                     // u = cb0^T@WA ; c = cb1^T@L0 + lb0
        if (t < 10) {
            float su = 0.f, scv = 0.f;
            for (int k = 0; k < 100; ++k) {
                su  += cb0[k] * WA[k * 10 + t];
                scv += cb1[k] * L0[k * 10 + t];
            }
            uvec[t] = su;
            cvec[t] = scv + lb0[t];
        }
        return;
    }
    __shared__ float wz[1000];                   // wz = W0@WA (unscaled)
    for (int o = t; o < 1000; o += 256) {
        int i = o / 10, m = o % 10;
        float s = 0.f;
        for (int k = 0; k < 100; ++k) s += W0[i * 100 + k] * WA[k * 10 + m];
        wz[o] = s;
    }
    __syncthreads();
    int i = blockIdx.x * 64 + (t >> 2);          // 784 blocks cover [0, 50176)
    int sub = t & 3;                             // 4 threads per node
    // chunk split 25 = 7+6+6+6
    int k0 = (sub == 0) ? 0 : 7 + (sub - 1) * 6;
    int k1 = k0 + ((sub == 0) ? 7 : 6);
    float ss = 0.f;
    float h[10];
    #pragma unroll
    for (int m = 0; m < 10; ++m) h[m] = 0.f;
    if (i < NN) {
        const float4* r4 = (const float4*)(x + i * 100);
        for (int kk = k0; kk < k1; ++kk) {
            float4 a = r4[kk];
            ss += a.x * a.x + a.y * a.y + a.z * a.z + a.w * a.w;
            #pragma unroll
            for (int j = 0; j < 4; ++j) {
                float av = ((const float*)&a)[j];
                int k = kk * 4 + j;
                #pragma unroll
                for (int m = 0; m < 10; ++m) h[m] += av * wz[k * 10 + m];  // LDS broadcast
            }
        }
    }
    // combine 4 partial h across the node's 4 threads (butterfly)
    #pragma unroll
    for (int m = 0; m < 10; ++m) {
        h[m] += __shfl_xor(h[m], 1, 64);
        h[m] += __shfl_xor(h[m], 2, 64);
    }
    // block-level sumsq reduction (all threads; i>=NN contribute 0)
    ss = wredf(ss);
    __shared__ float p[4];
    if ((t & 63) == 0) p[t >> 6] = ss;
    __syncthreads();
    if (t == 0) atomicAdd(acc, p[0] + p[1] + p[2] + p[3]);

    if (sub == 0) {
        if (i < NN) {
            float dv = rsqrtf((float)(cursor[i] + 1));
            float o16[16];
            #pragma unroll
            for (int m = 0; m < 10; ++m) o16[m] = dv * h[m];
            o16[10] = dv;
            o16[11] = o16[12] = o16[13] = o16[14] = o16[15] = 0.f;
            float4* dst4 = (float4*)(gp + i * 16);
            #pragma unroll
            for (int q = 0; q < 4; ++q) dst4[q] = *(float4*)&o16[q * 4];
        } else if (i == NN) {                    // dedicated zero row for masked gathers
            float4 z = {0.f, 0.f, 0.f, 0.f};
            float4* d4 = (float4*)(gp + NN * 16);
            d4[0] = z; d4[1] = z; d4[2] = z; d4[3] = z;
        }
    }
}

// ---- agg pass 1: 4 nodes per wave, rows/self/cursor prefetched, masked ILP-4 batches ----
// tb[n][c<10] = sc*dv_n^2*(gp_n + sum gp_j)[c]; tb[n][10] = dv_n*(dv_n + sum dv_j)
__global__ __launch_bounds__(256) void k_agg1(
    const float* __restrict__ gp, const int* __restrict__ cursor,
    const int* __restrict__ ell, const float* __restrict__ acc,
    float* __restrict__ tb)
{
    int w = (blockIdx.x * 256 + threadIdx.x) >> 6;   // wave id
    int l = threadIdx.x & 63, g = l >> 4, lane16 = l & 15;
    int n0 = w * 4;                              // 3126 blocks -> n0 max 50012
    // prefetch: 4 ELL rows (coalesced 256B each), 4 self rows, 4 degrees
    int rpl0 = ell[(n0 + 0) * ELLW + l];
    int rpl1 = ell[(n0 + 1) * ELLW + l];
    int rpl2 = ell[(n0 + 2) * ELLW + l];
    int rpl3 = ell[(n0 + 3) * ELLW + l];
    float sf0 = gp[(n0 + 0) * 16 + lane16];
    float sf1 = gp[(n0 + 1) * 16 + lane16];
    float sf2 = gp[(n0 + 2) * 16 + lane16];
    float sf3 = gp[(n0 + 3) * 16 + lane16];
    int cval = cursor[n0 + (l & 3)];
    float sc = rsqrtf(*acc);                     // 1/||x||, uniform
    #pragma unroll
    for (int j = 0; j < 4; ++j) {
        int n = n0 + j;
        if (n > NN) continue;                    // wave-uniform branch
        if (n == NN) {
            if (l < 16) tb[NN * 16 + lane16] = 0.f;
            continue;
        }
        int rpl  = (j == 0) ? rpl0 : (j == 1) ? rpl1 : (j == 2) ? rpl2 : rpl3;
        float sf = (j == 0) ? sf0  : (j == 1) ? sf1  : (j == 2) ? sf2  : sf3;
        int deg = __shfl(cval, j, 64);
        int lim = min(deg, ELLW);
        float dvn = rsqrtf((float)(deg + 1));
        float a0 = (g == 0) ? sf : 0.f;          // self term
        float a1 = 0.f, a2 = 0.f, a3 = 0.f;
        int nb = (lim + 15) >> 4;                // 16-slot batches; typical 1-2
        for (int b = 0; b < nb; ++b) {
            int s0 = b * 16 + g;
            int v0 = __shfl(rpl, s0,      64);
            int v1 = __shfl(rpl, s0 + 4,  64);
            int v2 = __shfl(rpl, s0 + 8,  64);
            int v3 = __shfl(rpl, s0 + 12, 64);
            int i0 = (s0      < lim) ? v0 : NN;  // masked -> zero row
            int i1 = (s0 + 4  < lim) ? v1 : NN;
            int i2 = (s0 + 8  < lim) ? v2 : NN;
            int i3 = (s0 + 12 < lim) ? v3 : NN;
            a0 += gp[i0 * 16 + lane16];          // 4 gathers in flight
            a1 += gp[i1 * 16 + lane16];
            a2 += gp[i2 * 16 + lane16];
            a3 += gp[i3 * 16 + lane16];
        }
        float s = (a0 + a1) + (a2 + a3);
        s += __shfl_xor(s, 16, 64);
        s += __shfl_xor(s, 32, 64);
        if (l < 16) {
            float o = (lane16 < 10) ? sc * dvn * dvn * s
                                    : (lane16 == 10 ? dvn * s : 0.f);
            tb[n * 16 + lane16] = o;
        }
    }
}

// ---- agg pass 2: same structure + rank-1 bias + ReLU + 10->1 head ----
// grid exactly 3125 blocks x 4 waves x 4 nodes = 50000: no bounds guards needed
__global__ __launch_bounds__(256) void k_agg2(
    const float* __restrict__ tb, const int* __restrict__ cursor,
    const int* __restrict__ ell, const float* __restrict__ uvec,
    const float* __restrict__ cvec, const float* __restrict__ L1,
    const float* __restrict__ lb1, float* __restrict__ out)
{
    __shared__ float su[10], scv[10], sl[10];
    if (threadIdx.x < 10) {
        su[threadIdx.x]  = uvec[threadIdx.x];
        scv[threadIdx.x] = cvec[threadIdx.x];
        sl[threadIdx.x]  = L1[threadIdx.x];
    }
    __syncthreads();
    int w = (blockIdx.x * 256 + threadIdx.x) >> 6;
    int l = threadIdx.x & 63, g = l >> 4, lane16 = l & 15;
    int n0 = w * 4;
    int rpl0 = ell[(n0 + 0) * ELLW + l];
    int rpl1 = ell[(n0 + 1) * ELLW + l];
    int rpl2 = ell[(n0 + 2) * ELLW + l];
    int rpl3 = ell[(n0 + 3) * ELLW + l];
    float sf0 = tb[(n0 + 0) * 16 + lane16];
    float sf1 = tb[(n0 + 1) * 16 + lane16];
    float sf2 = tb[(n0 + 2) * 16 + lane16];
    float sf3 = tb[(n0 + 3) * 16 + lane16];
    int cval = cursor[n0 + (l & 3)];
    float blb1 = lb1[0];
    #pragma unroll
    for (int j = 0; j < 4; ++j) {
        int n = n0 + j;
        int rpl  = (j == 0) ? rpl0 : (j == 1) ? rpl1 : (j == 2) ? rpl2 : rpl3;
        float sf = (j == 0) ? sf0  : (j == 1) ? sf1  : (j == 2) ? sf2  : sf3;
        int deg = __shfl(cval, j, 64);
        int lim = min(deg, ELLW);
        float dvn = rsqrtf((float)(deg + 1));
        float a0 = (g == 0) ? sf : 0.f;          // self term (tb pre-scaled)
        float a1 = 0.f, a2 = 0.f, a3 = 0.f;
        int nb = (lim + 15) >> 4;
        for (int b = 0; b < nb; ++b) {
            int s0 = b * 16 + g;
            int v0 = __shfl(rpl, s0,      64);
            int v1 = __shfl(rpl, s0 + 4,  64);
            int v2 = __shfl(rpl, s0 + 8,  64);
            int v3 = __shfl(rpl, s0 + 12, 64);
            int i0 = (s0      < lim) ? v0 : NN;
            int i1 = (s0 + 4  < lim) ? v1 : NN;
            int i2 = (s0 + 8  < lim) ? v2 : NN;
            int i3 = (s0 + 12 < lim) ? v3 : NN;
            a0 += tb[i0 * 16 + lane16];
            a1 += tb[i1 * 16 + lane16];
            a2 += tb[i2 * 16 + lane16];
            a3 += tb[i3 * 16 + lane16];
        }
        float s = (a0 + a1) + (a2 + a3);
        s += __shfl_xor(s, 16, 64);
        s += __shfl_xor(s, 32, 64);
        if (l < 16) {
            float v = (j == 0) ? __shfl(sf0, 10, 64) : (j == 1) ? __shfl(sf1, 10, 64)
                     : (j == 2) ? __shfl(sf2, 10, 64) : __shfl(sf3, 10, 64);  // v_n = tb[n][10]
            float hidden = 0.f;
            if (lane16 < 10)
                hidden = fmaxf(dvn * s + v * su[lane16] + scv[lane16], 0.f) * sl[lane16];
            #pragma unroll
            for (int o = 8; o; o >>= 1) hidden += __shfl_down(hidden, o, 16);
            if (lane16 == 0) out[n] = hidden + blb1;
        }
    }
}

extern "C" void kernel_launch(void* const* d_in, const int* in_sizes, int n_in,
                              void* d_out, int out_size, void* d_ws, size_t ws_size,
                              hipStream_t stream) {
    const float* x   = (const float*)d_in[0];
    const int*   ei  = (const int*)d_in[1];
    const int*   src = ei;            // edge_index[0]
    const int*   dst = ei + NE;       // edge_index[1]
    const float* W0  = (const float*)d_in[2];
    const float* cb0 = (const float*)d_in[3];
    const float* W1  = (const float*)d_in[4];
    const float* cb1 = (const float*)d_in[5];
    const float* lw0 = (const float*)d_in[6];
    const float* lb0 = (const float*)d_in[7];
    const float* lw1 = (const float*)d_in[8];
    const float* lb1 = (const float*)d_in[9];
    float* out = (float*)d_out;

    // workspace layout (bytes); zero-zone [0, 200320) memset each call
    char* ws = (char*)d_ws;
    float* acc   = (float*)(ws + 0);          // 4B
    int*   cursor= (int*)  (ws + 256);        // (NN+1)*4; cursor[NN] stays 0
    const size_t zspan = 200320;
    float* uvec  = (float*)(ws + 200448);     // 40B
    float* cvec  = (float*)(ws + 200576);     // 40B
    int*   ell   = (int*)  (ws + 200704);     // NN*64*4 = 12.8MB -> 13000704
    float* gp    = (float*)(ws + 13000704);   // (NN+1)*16*4 -> 16200768
    float* tb    = (float*)(ws + 16200768);   // (NN+1)*16*4 -> 19400832 total (~19.4MB)

    hipMemsetAsync(d_ws, 0, zspan, stream);
    k_fill <<<3125, 256, 0, stream>>>(src, dst, cursor, ell);
    k_proj <<<785, 256, 0, stream>>>(x, W0, W1, cb0, cb1, lw0, lb0,
                                     cursor, acc, uvec, cvec, gp);
    k_agg1 <<<3126, 256, 0, stream>>>(gp, cursor, ell, acc, tb);
    k_agg2 <<<3125, 256, 0, stream>>>(tb, cursor, ell, uvec, cvec, lw1, lb1, out);
}

// Round 14
// 203.978 us; speedup vs baseline: 1.1300x; 1.1300x over previous
//
#include <hip/hip_runtime.h>

#define NN 50000
#define NE 800000
#define ELLW 64

__device__ __forceinline__ float wredf(float v) {
    #pragma unroll
    for (int o = 32; o > 0; o >>= 1) v += __shfl_down(v, o, 64);
    return v;
}

// ---- one-block weight collapse: Wz = W0@W1@L0, uvec = cb0^T@(W1@L0), cvec = cb1^T@L0 + lb0 ----
__global__ __launch_bounds__(256) void k_wprep(
    const float* __restrict__ W0, const float* __restrict__ W1,
    const float* __restrict__ cb0, const float* __restrict__ cb1,
    const float* __restrict__ L0, const float* __restrict__ lb0,
    float* __restrict__ Wz, float* __restrict__ uvec, float* __restrict__ cvec)
{
    __shared__ float WA[1000];                   // W1@L0 [100][10]
    int t = threadIdx.x;
    for (int o = t; o < 1000; o += 256) {
        int j = o / 10, m = o % 10;
        float s = 0.f;
        for (int k = 0; k < 100; ++k) s += W1[j * 100 + k] * L0[k * 10 + m];
        WA[o] = s;
    }
    __syncthreads();
    for (int o = t; o < 1000; o += 256) {        // Wz = W0@WA (unscaled)
        int i = o / 10, m = o % 10;
        float s = 0.f;
        for (int k = 0; k < 100; ++k) s += W0[i * 100 + k] * WA[k * 10 + m];
        Wz[o] = s;
    }
    if (t < 10) {
        float su = 0.f, scv = 0.f;
        for (int k = 0; k < 100; ++k) {
            su  += cb0[k] * WA[k * 10 + t];
            scv += cb1[k] * L0[k * 10 + t];
        }
        uvec[t] = su;
        cvec[t] = scv + lb0[t];
    }
}

// ---- ELL fill: R4-proven minimal shape (VGPR ~4, no LDS, max occupancy) ----
__global__ __launch_bounds__(256) void k_fill(
    const int* __restrict__ src, const int* __restrict__ dst,
    int* __restrict__ cursor, int* __restrict__ ell)
{
    int e = blockIdx.x * 256 + threadIdx.x;      // 3125*256 == NE exactly
    int s = src[e];
    int d = dst[e];
    int p = atomicAdd(&cursor[d], 1);            // compact cursor: proven 46us config
    if (p < ELLW) ell[d * ELLW + p] = s;         // deg max ~45 << 64
}

// ---- projection: 4 threads/node, Wz from global (4KB LDS), fused sumsq ----
// 784 blocks x 64 nodes cover [0, 50176) — includes zero row NN.
__global__ __launch_bounds__(256) void k_proj(
    const float* __restrict__ x, const float* __restrict__ Wz,
    const int* __restrict__ cursor, float* __restrict__ acc,
    float* __restrict__ gp)
{
    __shared__ float wz[1000];
    int t = threadIdx.x;
    for (int o = t; o < 1000; o += 256) wz[o] = Wz[o];
    __syncthreads();
    int i = blockIdx.x * 64 + (t >> 2);
    int sub = t & 3;                             // 4 threads per node
    int k0 = (sub == 0) ? 0 : 7 + (sub - 1) * 6; // chunks 7/6/6/6
    int k1 = k0 + ((sub == 0) ? 7 : 6);
    float ss = 0.f;
    float h[10];
    #pragma unroll
    for (int m = 0; m < 10; ++m) h[m] = 0.f;
    if (i < NN) {
        const float4* r4 = (const float4*)(x + i * 100);
        for (int kk = k0; kk < k1; ++kk) {
            float4 a = r4[kk];
            ss += a.x * a.x + a.y * a.y + a.z * a.z + a.w * a.w;
            #pragma unroll
            for (int j = 0; j < 4; ++j) {
                float av = ((const float*)&a)[j];
                int k = kk * 4 + j;
                #pragma unroll
                for (int m = 0; m < 10; ++m) h[m] += av * wz[k * 10 + m];  // LDS broadcast
            }
        }
    }
    // combine the node's 4 partial h (quad-local butterfly)
    #pragma unroll
    for (int m = 0; m < 10; ++m) {
        h[m] += __shfl_xor(h[m], 1, 64);
        h[m] += __shfl_xor(h[m], 2, 64);
    }
    // block-level sumsq reduction (i>=NN contribute 0)
    ss = wredf(ss);
    __shared__ float p[4];
    if ((t & 63) == 0) p[t >> 6] = ss;
    __syncthreads();
    if (t == 0) atomicAdd(acc, p[0] + p[1] + p[2] + p[3]);

    if (sub == 0) {
        if (i < NN) {
            float dv = rsqrtf((float)(cursor[i] + 1));
            float o16[16];
            #pragma unroll
            for (int m = 0; m < 10; ++m) o16[m] = dv * h[m];
            o16[10] = dv;
            o16[11] = o16[12] = o16[13] = o16[14] = o16[15] = 0.f;
            float4* dst4 = (float4*)(gp + i * 16);
            #pragma unroll
            for (int q = 0; q < 4; ++q) dst4[q] = *(float4*)&o16[q * 4];
        } else if (i == NN) {                    // dedicated zero row for masked gathers
            float4 z = {0.f, 0.f, 0.f, 0.f};
            float4* d4 = (float4*)(gp + NN * 16);
            d4[0] = z; d4[1] = z; d4[2] = z; d4[3] = z;
        }
    }
}

// ---- agg pass 1: 4 nodes per wave, rows/self/cursor prefetched, masked ILP-4 batches ----
// tb[n][c<10] = sc*dv_n^2*(gp_n + sum gp_j)[c]; tb[n][10] = dv_n*(dv_n + sum dv_j)
__global__ __launch_bounds__(256) void k_agg1(
    const float* __restrict__ gp, const int* __restrict__ cursor,
    const int* __restrict__ ell, const float* __restrict__ acc,
    float* __restrict__ tb)
{
    int w = (blockIdx.x * 256 + threadIdx.x) >> 6;   // wave id
    int l = threadIdx.x & 63, g = l >> 4, lane16 = l & 15;
    int n0 = w * 4;
    int rpl0 = ell[(n0 + 0) * ELLW + l];
    int rpl1 = ell[(n0 + 1) * ELLW + l];
    int rpl2 = ell[(n0 + 2) * ELLW + l];
    int rpl3 = ell[(n0 + 3) * ELLW + l];
    float sf0 = gp[(n0 + 0) * 16 + lane16];
    float sf1 = gp[(n0 + 1) * 16 + lane16];
    float sf2 = gp[(n0 + 2) * 16 + lane16];
    float sf3 = gp[(n0 + 3) * 16 + lane16];
    int cval = cursor[n0 + (l & 3)];
    float sc = rsqrtf(*acc);                     // 1/||x||, uniform
    #pragma unroll
    for (int j = 0; j < 4; ++j) {
        int n = n0 + j;
        if (n > NN) continue;                    // wave-uniform
        if (n == NN) {
            if (l < 16) tb[NN * 16 + lane16] = 0.f;
            continue;
        }
        int rpl  = (j == 0) ? rpl0 : (j == 1) ? rpl1 : (j == 2) ? rpl2 : rpl3;
        float sf = (j == 0) ? sf0  : (j == 1) ? sf1  : (j == 2) ? sf2  : sf3;
        int deg = __shfl(cval, j, 64);
        int lim = min(deg, ELLW);
        float dvn = rsqrtf((float)(deg + 1));
        float a0 = (g == 0) ? sf : 0.f;          // self term
        float a1 = 0.f, a2 = 0.f, a3 = 0.f;
        int nb = (lim + 15) >> 4;                // 16-slot batches; typical 1-2
        for (int b = 0; b < nb; ++b) {
            int s0 = b * 16 + g;
            int v0 = __shfl(rpl, s0,      64);
            int v1 = __shfl(rpl, s0 + 4,  64);
            int v2 = __shfl(rpl, s0 + 8,  64);
            int v3 = __shfl(rpl, s0 + 12, 64);
            int i0 = (s0      < lim) ? v0 : NN;  // masked -> zero row
            int i1 = (s0 + 4  < lim) ? v1 : NN;
            int i2 = (s0 + 8  < lim) ? v2 : NN;
            int i3 = (s0 + 12 < lim) ? v3 : NN;
            a0 += gp[i0 * 16 + lane16];          // 4 gathers in flight
            a1 += gp[i1 * 16 + lane16];
            a2 += gp[i2 * 16 + lane16];
            a3 += gp[i3 * 16 + lane16];
        }
        float s = (a0 + a1) + (a2 + a3);
        s += __shfl_xor(s, 16, 64);
        s += __shfl_xor(s, 32, 64);
        if (l < 16) {
            float o = (lane16 < 10) ? sc * dvn * dvn * s
                                    : (lane16 == 10 ? dvn * s : 0.f);
            tb[n * 16 + lane16] = o;
        }
    }
}

// ---- agg pass 2: same structure + rank-1 bias + ReLU + 10->1 head ----
__global__ __launch_bounds__(256) void k_agg2(
    const float* __restrict__ tb, const int* __restrict__ cursor,
    const int* __restrict__ ell, const float* __restrict__ uvec,
    const float* __restrict__ cvec, const float* __restrict__ L1,
    const float* __restrict__ lb1, float* __restrict__ out)
{
    __shared__ float su[10], scv[10], sl[10];
    if (threadIdx.x < 10) {
        su[threadIdx.x]  = uvec[threadIdx.x];
        scv[threadIdx.x] = cvec[threadIdx.x];
        sl[threadIdx.x]  = L1[threadIdx.x];
    }
    __syncthreads();
    int w = (blockIdx.x * 256 + threadIdx.x) >> 6;
    int l = threadIdx.x & 63, g = l >> 4, lane16 = l & 15;
    int n0 = w * 4;                              // grid exactly 50000 nodes
    int rpl0 = ell[(n0 + 0) * ELLW + l];
    int rpl1 = ell[(n0 + 1) * ELLW + l];
    int rpl2 = ell[(n0 + 2) * ELLW + l];
    int rpl3 = ell[(n0 + 3) * ELLW + l];
    float sf0 = tb[(n0 + 0) * 16 + lane16];
    float sf1 = tb[(n0 + 1) * 16 + lane16];
    float sf2 = tb[(n0 + 2) * 16 + lane16];
    float sf3 = tb[(n0 + 3) * 16 + lane16];
    int cval = cursor[n0 + (l & 3)];
    float blb1 = lb1[0];
    #pragma unroll
    for (int j = 0; j < 4; ++j) {
        int n = n0 + j;
        int rpl  = (j == 0) ? rpl0 : (j == 1) ? rpl1 : (j == 2) ? rpl2 : rpl3;
        float sf = (j == 0) ? sf0  : (j == 1) ? sf1  : (j == 2) ? sf2  : sf3;
        int deg = __shfl(cval, j, 64);
        int lim = min(deg, ELLW);
        float dvn = rsqrtf((float)(deg + 1));
        float a0 = (g == 0) ? sf : 0.f;          // self term (tb pre-scaled)
        float a1 = 0.f, a2 = 0.f, a3 = 0.f;
        int nb = (lim + 15) >> 4;
        for (int b = 0; b < nb; ++b) {
            int s0 = b * 16 + g;
            int v0 = __shfl(rpl, s0,      64);
            int v1 = __shfl(rpl, s0 + 4,  64);
            int v2 = __shfl(rpl, s0 + 8,  64);
            int v3 = __shfl(rpl, s0 + 12, 64);
            int i0 = (s0      < lim) ? v0 : NN;
            int i1 = (s0 + 4  < lim) ? v1 : NN;
            int i2 = (s0 + 8  < lim) ? v2 : NN;
            int i3 = (s0 + 12 < lim) ? v3 : NN;
            a0 += tb[i0 * 16 + lane16];
            a1 += tb[i1 * 16 + lane16];
            a2 += tb[i2 * 16 + lane16];
            a3 += tb[i3 * 16 + lane16];
        }
        float s = (a0 + a1) + (a2 + a3);
        s += __shfl_xor(s, 16, 64);
        s += __shfl_xor(s, 32, 64);
        if (l < 16) {
            float v = (j == 0) ? __shfl(sf0, 10, 64) : (j == 1) ? __shfl(sf1, 10, 64)
                     : (j == 2) ? __shfl(sf2, 10, 64) : __shfl(sf3, 10, 64);  // v_n
            float hidden = 0.f;
            if (lane16 < 10)
                hidden = fmaxf(dvn * s + v * su[lane16] + scv[lane16], 0.f) * sl[lane16];
            #pragma unroll
            for (int o = 8; o; o >>= 1) hidden += __shfl_down(hidden, o, 16);
            if (lane16 == 0) out[n] = hidden + blb1;
        }
    }
}

extern "C" void kernel_launch(void* const* d_in, const int* in_sizes, int n_in,
                              void* d_out, int out_size, void* d_ws, size_t ws_size,
                              hipStream_t stream) {
    const float* x   = (const float*)d_in[0];
    const int*   ei  = (const int*)d_in[1];
    const int*   src = ei;            // edge_index[0]
    const int*   dst = ei + NE;       // edge_index[1]
    const float* W0  = (const float*)d_in[2];
    const float* cb0 = (const float*)d_in[3];
    const float* W1  = (const float*)d_in[4];
    const float* cb1 = (const float*)d_in[5];
    const float* lw0 = (const float*)d_in[6];
    const float* lb0 = (const float*)d_in[7];
    const float* lw1 = (const float*)d_in[8];
    const float* lb1 = (const float*)d_in[9];
    float* out = (float*)d_out;

    // workspace layout (bytes); zero-zone [0, 200320) memset each call
    char* ws = (char*)d_ws;
    float* acc   = (float*)(ws + 0);          // 4B
    int*   cursor= (int*)  (ws + 256);        // (NN+1)*4; cursor[NN] stays 0
    const size_t zspan = 200320;
    float* Wz    = (float*)(ws + 200448);     // 4000B
    float* uvec  = (float*)(ws + 204544);     // 40B
    float* cvec  = (float*)(ws + 204672);     // 40B
    int*   ell   = (int*)  (ws + 204800);     // NN*64*4 = 12.8MB -> 13004800
    float* gp    = (float*)(ws + 13004800);   // (NN+1)*16*4 -> 16204864
    float* tb    = (float*)(ws + 16204864);   // (NN+1)*16*4 -> 19404928 total (~19.4MB)

    hipMemsetAsync(d_ws, 0, zspan, stream);
    k_wprep <<<1, 256, 0, stream>>>(W0, W1, cb0, cb1, lw0, lb0, Wz, uvec, cvec);
    k_fill  <<<3125, 256, 0, stream>>>(src, dst, cursor, ell);
    k_proj  <<<784, 256, 0, stream>>>(x, Wz, cursor, acc, gp);
    k_agg1  <<<3126, 256, 0, stream>>>(gp, cursor, ell, acc, tb);
    k_agg2  <<<3125, 256, 0, stream>>>(tb, cursor, ell, uvec, cvec, lw1, lb1, out);
}